// Round 11
// baseline (334.679 us; speedup 1.0000x reference)
//
#include <hip/hip_runtime.h>

// ---------------------------------------------------------------------------
// TiedRowAxialAttention on MI355X (gfx950), bf16 MFMA pipeline.
// dims: b=4 rows=64 t=256 dim=512 heads=8 dim_head=64 ; scale = 1/64
// stages:
//   prep:   W_qkv permuted (d,k,h)->(k,h,d) + bf16 ; W0->bf16   (one kernel)
//   gemm1:  qkv = x @ Wp^T, x read DIRECTLY as fp32 (cast fused into A-staging
//           via reg-stage: float4 loads -> f2bf -> ds_write_b64, same rotated
//           LDS layout). -> Q[bh][i][rd], K[bh][j][rd], Vt[bh][rd][j]
//   gemm_s: S[bh][i][j] = sum_rd Q K (batched NT, split-K=4, fp32 partials)
//   softmax: wave-per-row, P = softmax(S/64) bf16 (rinv folded in)
//   gemm_pv: O = P V via A=Vt,B=P -> O2[(b,r,i)][hd]
//   gemm2:  out = O2 @ W0^T -> fp32
// GEMM mainloop (R7-proven): 256x128 tile, BK=32, 4 waves (2Mx2N, per-wave
// 128x64, acc[8][4]), 3 LDS buffers (72 KB, 2 blk/CU), 2-tile prefetch lead,
// counted vmcnt (never 0 mid-loop), one barrier per K-tile.
// qkv vmcnt ledger (per thread/iter: 8 float4 A + 2 gload B):
//   end of iter g waits vmcnt(2) -> drains B(g+1)+A(g+2), leaves B(g+2);
//   lgkmcnt(0) before barrier makes iter-g ds_writes (A tile g+1) visible.
// NOTE: no pointer ARRAYS initialized from the __shared__ symbol (gfx950
// rejects the addrspacecast static initializer) — use integer offsets.
// ---------------------------------------------------------------------------

typedef short  bf16x8 __attribute__((ext_vector_type(8)));
typedef float  f32x4  __attribute__((ext_vector_type(4)));

#define MFMA16(a,b,c) __builtin_amdgcn_mfma_f32_16x16x32_bf16((a),(b),(c),0,0,0)

__device__ __forceinline__ ushort f2bf(float f) {
  union { float f; unsigned u; } v; v.f = f;
  unsigned r = v.u + 0x7fffu + ((v.u >> 16) & 1u);   // RNE
  return (ushort)(r >> 16);
}

__device__ __forceinline__ void gload_lds16(const void* g, void* lds) {
  __builtin_amdgcn_global_load_lds(
      (const __attribute__((address_space(1))) void*)g,
      (__attribute__((address_space(3))) void*)lds, 16, 0, 0);
}

// -------------------------------- prep -------------------------------------
// blocks 0..767: permute W_qkv (2 rows per block); blocks 768..831: cast W0.

__global__ void prep_k(const float* __restrict__ W, ushort* __restrict__ Wp,
                       const float* __restrict__ W0, ushort* __restrict__ W0b) {
  const int bid = blockIdx.x, tid = threadIdx.x;
  if (bid < 768) {
    int np = (bid << 1) + (tid >> 7);       // 0..1535
    int c  = tid & 127;
    int k = np >> 9, h = (np >> 6) & 7, d = np & 63;
    float4 f = reinterpret_cast<const float4*>(
        W + (size_t)(d * 24 + k * 8 + h) * 512)[c];
    ushort4 u; u.x = f2bf(f.x); u.y = f2bf(f.y); u.z = f2bf(f.z); u.w = f2bf(f.w);
    reinterpret_cast<ushort4*>(Wp + (size_t)np * 512)[c] = u;
  } else {
    int v0 = ((bid - 768) << 10) + (tid << 2);    // 64 blocks x 1024 f4
#pragma unroll
    for (int q = 0; q < 4; ++q) {
      int v = v0 + q;
      float4 f = reinterpret_cast<const float4*>(W0)[v];
      ushort4 u; u.x = f2bf(f.x); u.y = f2bf(f.y); u.z = f2bf(f.z); u.w = f2bf(f.w);
      reinterpret_cast<ushort4*>(W0b)[v] = u;
    }
  }
}

// ================== 256x128 pipelined NT mainloop (4 waves) =================
// (generic bf16 version, R7-proven; used by gemm_s / gemm_pv / gemm_out)

__device__ __forceinline__ void gemm_nt_256x128(
    const ushort* __restrict__ A, const ushort* __restrict__ B,
    int lda, int ldb, int P, int m0, int n0, char* lds, f32x4 (&acc)[8][4]) {
  const int tid = threadIdx.x;
  const int w = tid >> 6, l = tid & 63;
  const int il = l & 15, kl = l >> 4;
  const int wm = w >> 1, wn = w & 1;

  auto stageA = [&](char* buf, int kt) {
#pragma unroll
    for (int c = 0; c < 4; ++c) {
      int rbase = (w << 6) + (c << 4);                     // wave-uniform
      int row = rbase + (l >> 2);
      int s = ((l & 3) - ((row >> 1) & 3)) & 3;
      gload_lds16(A + (size_t)(m0 + row) * lda + (kt << 5) + (s << 3),
                  buf + rbase * 64);
    }
  };
  auto stageB = [&](char* buf, int kt) {
#pragma unroll
    for (int c = 0; c < 2; ++c) {
      int rbase = (w << 5) + (c << 4);                     // wave-uniform
      int row = rbase + (l >> 2);
      int s = ((l & 3) - ((row >> 1) & 3)) & 3;
      gload_lds16(B + (size_t)(n0 + row) * ldb + (kt << 5) + (s << 3),
                  buf + 16384 + rbase * 64);
    }
  };
  auto loadA8 = [&](const char* buf, bf16x8 (&af)[8]) {
#pragma unroll
    for (int q = 0; q < 8; ++q) {
      int row = (wm << 7) + (q << 4) + il;
      af[q] = *(const bf16x8*)(buf + row * 64 + (((kl + (row >> 1)) & 3) << 4));
    }
  };
  auto loadB4 = [&](const char* buf, bf16x8 (&bfr)[4]) {
#pragma unroll
    for (int q = 0; q < 4; ++q) {
      int row = (wn << 6) + (q << 4) + il;
      bfr[q] = *(const bf16x8*)(buf + 16384 + row * 64 + (((kl + (row >> 1)) & 3) << 4));
    }
  };

#pragma unroll
  for (int i = 0; i < 8; ++i)
#pragma unroll
    for (int j = 0; j < 4; ++j) acc[i][j] = f32x4{0.f, 0.f, 0.f, 0.f};

  stageA(lds, 0);         stageB(lds, 0);
  stageA(lds + 24576, 1); stageB(lds + 24576, 1);
  asm volatile("s_waitcnt vmcnt(6)" ::: "memory");
  __builtin_amdgcn_s_barrier();

  int cur = 0, nx = 2;
  for (int g = 0; g < P; ++g) {
    char* cbuf = lds + cur * 24576;
    char* sbuf = lds + nx * 24576;
    bf16x8 af[8], bfr[4];
    loadA8(cbuf, af);
    loadB4(cbuf, bfr);
    if (g + 2 < P) { stageA(sbuf, g + 2); stageB(sbuf, g + 2); }
    __builtin_amdgcn_s_setprio(1);
#pragma unroll
    for (int fm = 0; fm < 8; ++fm)
#pragma unroll
      for (int fn = 0; fn < 4; ++fn)
        acc[fm][fn] = MFMA16(af[fm], bfr[fn], acc[fm][fn]);
    __builtin_amdgcn_s_setprio(0);
    if (g + 2 < P) asm volatile("s_waitcnt vmcnt(6)" ::: "memory");
    else           asm volatile("s_waitcnt vmcnt(0)" ::: "memory");
    __builtin_amdgcn_s_barrier();
    cur = (cur == 2) ? 0 : cur + 1;
    nx  = (nx  == 2) ? 0 : nx  + 1;
  }
}

// ------------------------------- gemm1 (qkv) --------------------------------
// A = x fp32 (cast fused: reg-stage float4 -> f2bf -> ds_write into the same
// rotated LDS layout). B = Wp bf16 via gload_lds. 3072 blocks.

__global__ __launch_bounds__(256, 2) void gemm_qkv_k(
    const float* __restrict__ x, const ushort* __restrict__ Wp,
    ushort* __restrict__ Qb, ushort* __restrict__ Kb, ushort* __restrict__ Vt) {
  __shared__ __align__(16) char lds_s[73728];
  char* lds = lds_s;                            // generic pointer, no array init
  f32x4 acc[8][4];
  const int Bid = blockIdx.x;
  const int xcd = Bid & 7, idx = Bid >> 3;
  const int nt = idx % 12, pl = idx / 12;       // pl 0..31
  const int m0 = ((pl << 3) + xcd) << 8;        // 256 m-tiles * 256
  const int n0 = nt << 7;

  const int tid = threadIdx.x, w = tid >> 6, l = tid & 63;
  const int il = l & 15, kl = l >> 4;
  const int wm = w >> 1, wn = w & 1;

  float4 ar[8];                                 // in-flight A K-tile (fp32)
  auto loadAx = [&](int kt) {
#pragma unroll
    for (int rd = 0; rd < 8; ++rd) {
      int row = (rd << 5) + (w << 3) + (l >> 3);
      ar[rd] = *reinterpret_cast<const float4*>(
          x + (size_t)(m0 + row) * 512 + (kt << 5) + ((l & 7) << 2));
    }
  };
  auto writeA = [&](char* buf) {                // rotated layout, 8B stores
#pragma unroll
    for (int rd = 0; rd < 8; ++rd) {
      int row = (rd << 5) + (w << 3) + (l >> 3);
      int c = l & 7;
      int slot = (((c >> 1) + (row >> 1)) & 3);
      ushort4 h;
      h.x = f2bf(ar[rd].x); h.y = f2bf(ar[rd].y);
      h.z = f2bf(ar[rd].z); h.w = f2bf(ar[rd].w);
      *reinterpret_cast<ushort4*>(buf + row * 64 + (slot << 4) + ((c & 1) << 3)) = h;
    }
  };
  auto stageB = [&](char* buf, int kt) {
#pragma unroll
    for (int c = 0; c < 2; ++c) {
      int rbase = (w << 5) + (c << 4);
      int row = rbase + (l >> 2);
      int s = ((l & 3) - ((row >> 1) & 3)) & 3;
      gload_lds16(Wp + (size_t)(n0 + row) * 512 + (kt << 5) + (s << 3),
                  buf + 16384 + rbase * 64);
    }
  };
  auto loadA8 = [&](const char* buf, bf16x8 (&af)[8]) {
#pragma unroll
    for (int q = 0; q < 8; ++q) {
      int row = (wm << 7) + (q << 4) + il;
      af[q] = *(const bf16x8*)(buf + row * 64 + (((kl + (row >> 1)) & 3) << 4));
    }
  };
  auto loadB4 = [&](const char* buf, bf16x8 (&bfr)[4]) {
#pragma unroll
    for (int q = 0; q < 4; ++q) {
      int row = (wn << 6) + (q << 4) + il;
      bfr[q] = *(const bf16x8*)(buf + 16384 + row * 64 + (((kl + (row >> 1)) & 3) << 4));
    }
  };

#pragma unroll
  for (int i = 0; i < 8; ++i)
#pragma unroll
    for (int j = 0; j < 4; ++j) acc[i][j] = f32x4{0.f, 0.f, 0.f, 0.f};

  // prologue: A(0)->LDS, A(1)->regs, B(0)/B(1) staged.
  loadAx(0);
  asm volatile("s_waitcnt vmcnt(0)" ::: "memory");
  writeA(lds);
  loadAx(1);
  stageB(lds, 0); stageB(lds + 24576, 1);
  asm volatile("s_waitcnt vmcnt(2)" ::: "memory");   // A(1) regs + B(0) done
  asm volatile("s_waitcnt lgkmcnt(0)" ::: "memory"); // A(0) writes visible
  __builtin_amdgcn_s_barrier();

  int cur = 0;
  for (int g = 0; g < 16; ++g) {
    int wn1 = (cur == 2) ? 0 : cur + 1;         // buf index (g+1)%3
    int nx2 = (wn1 == 2) ? 0 : wn1 + 1;         // buf index (g+2)%3
    if (g + 1 < 16) writeA(lds + wn1 * 24576);  // ds_write A(g+1) from regs
    bf16x8 af[8], bfr[4];
    loadA8(lds + cur * 24576, af);
    loadB4(lds + cur * 24576, bfr);
    if (g + 2 < 16) { loadAx(g + 2); stageB(lds + nx2 * 24576, g + 2); }
    __builtin_amdgcn_s_setprio(1);
#pragma unroll
    for (int fm = 0; fm < 8; ++fm)
#pragma unroll
      for (int fn = 0; fn < 4; ++fn)
        acc[fm][fn] = MFMA16(af[fm], bfr[fn], acc[fm][fn]);
    __builtin_amdgcn_s_setprio(0);
    if (g + 2 < 16) asm volatile("s_waitcnt vmcnt(2)" ::: "memory");
    else            asm volatile("s_waitcnt vmcnt(0)" ::: "memory");
    asm volatile("s_waitcnt lgkmcnt(0)" ::: "memory");
    __builtin_amdgcn_s_barrier();
    cur = wn1;
  }

  // epilogue (R7 form, coalesced)
  const int kq = n0 >> 9;                       // block-uniform: 0=Q 1=K 2=V
  const int br = m0 >> 8, b = br >> 6, r = br & 63;
  if (kq < 2) {
    ushort* dstb = kq ? Kb : Qb;
#pragma unroll
    for (int fm = 0; fm < 8; ++fm)
#pragma unroll
      for (int fn = 0; fn < 4; ++fn) {
        int n = n0 + (wn << 6) + (fn << 4) + il;
        int h = (n >> 6) & 7, d = n & 63;
#pragma unroll
        for (int j = 0; j < 4; ++j) {
          int i = (wm << 7) + (fm << 4) + (kl << 2) + j;
          size_t dst = ((size_t)((((b << 3) + h) << 8) + i) << 12) + (r << 6) + d;
          dstb[dst] = f2bf(acc[fm][fn][j]);
        }
      }
  } else {
#pragma unroll
    for (int fm = 0; fm < 8; ++fm)
#pragma unroll
      for (int fn = 0; fn < 4; ++fn) {
        int n = n0 - 1024 + (wn << 6) + (fn << 4) + il;     // h*64+d
        int h = n >> 6, d = n & 63;
        int i0 = (wm << 7) + (fm << 4) + (kl << 2);
        size_t dst = (((size_t)((((b << 3) + h) << 12)) + (r << 6) + d) << 8) + i0;
        ushort4 pk; pk.x = f2bf(acc[fm][fn][0]); pk.y = f2bf(acc[fm][fn][1]);
        pk.z = f2bf(acc[fm][fn][2]); pk.w = f2bf(acc[fm][fn][3]);
        *reinterpret_cast<ushort4*>(&Vt[dst]) = pk;
      }
  }
}

// ------------------------------- gemm2 (out) --------------------------------

__global__ __launch_bounds__(256, 2) void gemm_out_k(
    const ushort* __restrict__ O2, const ushort* __restrict__ W0b,
    float* __restrict__ out) {
  __shared__ __align__(16) char lds[73728];
  f32x4 acc[8][4];
  const int Bid = blockIdx.x;
  const int xcd = Bid & 7, idx = Bid >> 3;
  const int nt = idx & 3, pl = idx >> 2;        // pl 0..31
  const int m0 = ((pl << 3) + xcd) << 8;
  const int n0 = nt << 7;
  gemm_nt_256x128(O2, W0b, 512, 512, 16, m0, n0, lds, acc);

  const int tid = threadIdx.x, w = tid >> 6, l = tid & 63;
  const int il = l & 15, kl = l >> 4;
  const int wm = w >> 1, wn = w & 1;
#pragma unroll
  for (int fm = 0; fm < 8; ++fm)
#pragma unroll
    for (int fn = 0; fn < 4; ++fn) {
      int n = n0 + (wn << 6) + (fn << 4) + il;
#pragma unroll
      for (int j = 0; j < 4; ++j) {
        int m = m0 + (wm << 7) + (fm << 4) + (kl << 2) + j;
        out[(size_t)m * 512 + n] = acc[fm][fn][j];
      }
    }
}

// ---------------------- gemm_s: S partials (split-K=4) ----------------------
// 256 blocks: nt = Bid&1, z = Bid>>1 (bh*4+ks). Each block: 256x128 slab of
// S over rd-range ks*1024..+1024 (P=32). Sp[z][i][j] fp32.

__global__ __launch_bounds__(256, 2) void gemm_s_k(
    const ushort* __restrict__ Qb, const ushort* __restrict__ Kb,
    float* __restrict__ Sp) {
  __shared__ __align__(16) char lds[73728];
  f32x4 acc[8][4];
  const int Bid = blockIdx.x;
  const int nt = Bid & 1, z = Bid >> 1;         // z 0..127
  const int bh = z >> 2, ks = z & 3;
  const int n0 = nt << 7;
  const size_t base = ((size_t)bh << 20) + ((size_t)ks << 10);
  gemm_nt_256x128(Qb + base, Kb + base, 4096, 4096, 32, 0, n0, lds, acc);

  const int tid = threadIdx.x, w = tid >> 6, l = tid & 63;
  const int il = l & 15, kl = l >> 4;
  const int wm = w >> 1, wn = w & 1;
  float* o = Sp + ((size_t)z << 16);
#pragma unroll
  for (int fm = 0; fm < 8; ++fm)
#pragma unroll
    for (int fn = 0; fn < 4; ++fn) {
      int n = n0 + (wn << 6) + (fn << 4) + il;
#pragma unroll
      for (int j = 0; j < 4; ++j) {
        int m = (wm << 7) + (fm << 4) + (kl << 2) + j;
        o[(size_t)m * 256 + n] = acc[fm][fn][j];
      }
    }
}

// ------------------------- softmax (wave per row) ---------------------------
// P[bh][i][j] = softmax_j(sum_{ks=0..3} Sp[4bh+ks] / 64), bf16 with 1/sum.

__global__ void softmax_k(const float* __restrict__ Sp, ushort* __restrict__ Pb) {
  const int w = threadIdx.x >> 6, l = threadIdx.x & 63;
  const int row = (blockIdx.x << 2) + w;        // 0..8191
  const int bh = row >> 8, i = row & 255;
  const float4* p0 = reinterpret_cast<const float4*>(
      Sp + (((size_t)bh << 2) << 16) + ((size_t)i << 8)) + l;
  float4 a = p0[0], b2 = p0[16384], c = p0[32768], d = p0[49152];
  const float scale = 0.015625f;
  float s0 = (a.x + b2.x + c.x + d.x) * scale;
  float s1 = (a.y + b2.y + c.y + d.y) * scale;
  float s2 = (a.z + b2.z + c.z + d.z) * scale;
  float s3 = (a.w + b2.w + c.w + d.w) * scale;
  float m = fmaxf(fmaxf(s0, s1), fmaxf(s2, s3));
#pragma unroll
  for (int d2 = 1; d2 < 64; d2 <<= 1) m = fmaxf(m, __shfl_xor(m, d2));
  float e0 = __expf(s0 - m), e1 = __expf(s1 - m);
  float e2 = __expf(s2 - m), e3 = __expf(s3 - m);
  float sum = e0 + e1 + e2 + e3;
#pragma unroll
  for (int d2 = 1; d2 < 64; d2 <<= 1) sum += __shfl_xor(sum, d2);
  float r = 1.0f / sum;
  ushort4 p; p.x = f2bf(e0 * r); p.y = f2bf(e1 * r);
  p.z = f2bf(e2 * r); p.w = f2bf(e3 * r);
  reinterpret_cast<ushort4*>(Pb + ((size_t)bh << 16) + ((size_t)i << 8))[l] = p;
}

// ---------------------- gemm_pv: O = P V  (A=Vt, B=P) -----------------------

__global__ __launch_bounds__(256, 2) void gemm_pv_k(
    const ushort* __restrict__ Vt, const ushort* __restrict__ Pb,
    ushort* __restrict__ O2) {
  __shared__ __align__(16) char lds[73728];
  f32x4 acc[8][4];
  const int Bid = blockIdx.x;
  const int xcd = Bid & 7, idx = Bid >> 3;      // idx 0..127
  const int sub = idx & 31, grp = idx >> 5;     // sub: mt*2+nt, grp 0..3
  const int bh = (grp << 3) + xcd, b = bh >> 3, h = bh & 7;
  const int m0 = (sub >> 1) << 8;               // rd tile (16 x 256)
  const int n0 = (sub & 1) << 7;                // i tile (2 x 128)
  gemm_nt_256x128(Vt + ((size_t)bh << 20), Pb + ((size_t)bh << 16),
                  256, 256, 8, m0, n0, lds, acc);

  const int tid = threadIdx.x, w = tid >> 6, l = tid & 63;
  const int il = l & 15, kl = l >> 4;
  const int wm = w >> 1, wn = w & 1;
#pragma unroll
  for (int fm = 0; fm < 8; ++fm) {
    int rd0 = m0 + (wm << 7) + (fm << 4) + (kl << 2);
    int r = rd0 >> 6, d0 = rd0 & 63;
#pragma unroll
    for (int fn = 0; fn < 4; ++fn) {
      int i = n0 + (wn << 6) + (fn << 4) + il;
      ushort4 pk; pk.x = f2bf(acc[fm][fn][0]); pk.y = f2bf(acc[fm][fn][1]);
      pk.z = f2bf(acc[fm][fn][2]); pk.w = f2bf(acc[fm][fn][3]);
      *reinterpret_cast<ushort4*>(
          O2 + ((size_t)((((b << 6) + r) << 8) + i) << 9) + (h << 6) + d0) = pk;
    }
  }
}

// ------------------------------- launcher -----------------------------------

extern "C" void kernel_launch(void* const* d_in, const int* in_sizes, int n_in,
                              void* d_out, int out_size, void* d_ws, size_t ws_size,
                              hipStream_t stream) {
  const float* x    = (const float*)d_in[0];
  const float* Wqkv = (const float*)d_in[1];
  const float* W0   = (const float*)d_in[2];
  float* out = (float*)d_out;

  char* ws = (char*)d_ws;
  ushort* Wp  = (ushort*)(ws + 67108864);         //  1,572,864
  ushort* W0b = (ushort*)(ws + 68681728);         //    524,288
  ushort* Qb  = (ushort*)(ws + 69206016);         // 67,108,864 (-> Pb)
  ushort* Kb  = (ushort*)(ws + 136314880);        // 67,108,864
  ushort* Vt  = (ushort*)(ws + 203423744);        // 67,108,864  -> total 270,532,608
  if (ws_size < 270532608ull) return;             // workspace too small: fail visibly

  prep_k<<<832, 256, 0, stream>>>(Wqkv, Wp, W0, W0b);

  gemm_qkv_k<<<3072, 256, 0, stream>>>(x, Wp, Qb, Kb, Vt);

  float*  Sp = (float*)ws;                        // region 0 (33.6 MB)
  ushort* Pb = Qb;                                // Qb dead after gemm_s (4.2 MB)
  ushort* O2 = (ushort*)ws;                       // Sp dead after softmax (64 MB)

  gemm_s_k<<<256, 256, 0, stream>>>(Qb, Kb, Sp);
  softmax_k<<<2048, 256, 0, stream>>>(Sp, Pb);
  gemm_pv_k<<<1024, 256, 0, stream>>>(Vt, Pb, O2);

  gemm_out_k<<<1024, 256, 0, stream>>>(O2, W0b, out);
}

// Round 12
// 309.806 us; speedup vs baseline: 1.0803x; 1.0803x over previous
//
#include <hip/hip_runtime.h>

// ---------------------------------------------------------------------------
// TiedRowAxialAttention on MI355X (gfx950), bf16 MFMA pipeline.
// dims: b=4 rows=64 t=256 dim=512 heads=8 dim_head=64 ; scale = 1/64
// stages:
//   cast_x: x -> bf16 (xb)
//   prep:   W_qkv permuted (d,k,h)->(k,h,d) + bf16 ; W0->bf16   (one kernel)
//   gemm1:  qkv = xb @ Wp^T -> Q[bh][i][rd], K[bh][j][rd], Vt[bh][rd][j]
//           Q/K epilogue: acc -> LDS [256][136] bf16 -> ushort8 (16B) stores
//           (128 scalar 2B stores/thread -> 16 wide stores, 128B runs/8 lanes)
//   gemm_s: S[bh][i][j] = sum_rd Q K (batched NT, split-K=4, fp32 partials)
//   softmax: wave-per-row, P = softmax(S/64) bf16 (rinv folded in)
//   gemm_pv: O = P V via A=Vt,B=P -> O2[(b,r,i)][hd]
//   gemm2:  out = O2 @ W0^T -> fp32
// GEMM mainloop (R7-proven): 256x128 tile, BK=32, 4 waves (2Mx2N, per-wave
// 128x64, acc[8][4]), 3 LDS buffers (72 KB, 2 blk/CU), 2-tile prefetch lead,
// counted vmcnt(6) (never 0 mid-loop), one barrier per K-tile, no forced
// lgkm drain (compiler emits fine-grained lgkmcnt).
// ---------------------------------------------------------------------------

typedef short  bf16x8 __attribute__((ext_vector_type(8)));
typedef float  f32x4  __attribute__((ext_vector_type(4)));

#define MFMA16(a,b,c) __builtin_amdgcn_mfma_f32_16x16x32_bf16((a),(b),(c),0,0,0)

__device__ __forceinline__ ushort f2bf(float f) {
  union { float f; unsigned u; } v; v.f = f;
  unsigned r = v.u + 0x7fffu + ((v.u >> 16) & 1u);   // RNE
  return (ushort)(r >> 16);
}

__device__ __forceinline__ void gload_lds16(const void* g, void* lds) {
  __builtin_amdgcn_global_load_lds(
      (const __attribute__((address_space(1))) void*)g,
      (__attribute__((address_space(3))) void*)lds, 16, 0, 0);
}

// -------------------------------- prep -------------------------------------

__global__ void cast_f32_to_bf16(const float* __restrict__ in,
                                 ushort* __restrict__ out, int n4) {
  int idx = blockIdx.x * blockDim.x + threadIdx.x;
  int stride = gridDim.x * blockDim.x;
  for (int v = idx; v < n4; v += stride) {
    float4 f = reinterpret_cast<const float4*>(in)[v];
    ushort4 o; o.x = f2bf(f.x); o.y = f2bf(f.y); o.z = f2bf(f.z); o.w = f2bf(f.w);
    reinterpret_cast<ushort4*>(out)[v] = o;
  }
}

// blocks 0..767: permute W_qkv (2 rows per block); blocks 768..831: cast W0.
__global__ void prep_k(const float* __restrict__ W, ushort* __restrict__ Wp,
                       const float* __restrict__ W0, ushort* __restrict__ W0b) {
  const int bid = blockIdx.x, tid = threadIdx.x;
  if (bid < 768) {
    int np = (bid << 1) + (tid >> 7);       // 0..1535
    int c  = tid & 127;
    int k = np >> 9, h = (np >> 6) & 7, d = np & 63;
    float4 f = reinterpret_cast<const float4*>(
        W + (size_t)(d * 24 + k * 8 + h) * 512)[c];
    ushort4 u; u.x = f2bf(f.x); u.y = f2bf(f.y); u.z = f2bf(f.z); u.w = f2bf(f.w);
    reinterpret_cast<ushort4*>(Wp + (size_t)np * 512)[c] = u;
  } else {
    int v0 = ((bid - 768) << 10) + (tid << 2);    // 64 blocks x 1024 f4
#pragma unroll
    for (int q = 0; q < 4; ++q) {
      int v = v0 + q;
      float4 f = reinterpret_cast<const float4*>(W0)[v];
      ushort4 u; u.x = f2bf(f.x); u.y = f2bf(f.y); u.z = f2bf(f.z); u.w = f2bf(f.w);
      reinterpret_cast<ushort4*>(W0b)[v] = u;
    }
  }
}

// ================== 256x128 pipelined NT mainloop (4 waves) =================
// C = A @ B^T ; A [M][lda], B [N][ldb] bf16 row-major, K = 32*P.
// 256 threads = 4 waves (2M x 2N), per-wave 128x64 out = acc[8][4].
// 3 LDS buffers (24KB each), 2-tile lead, vmcnt(6) per K-tile, 1 barrier/tile.
// LDS per-row slot rotation: slot t at row r holds k-slot (t - r>>1)&3.

__device__ __forceinline__ void gemm_nt_256x128(
    const ushort* __restrict__ A, const ushort* __restrict__ B,
    int lda, int ldb, int P, int m0, int n0, char* lds, f32x4 (&acc)[8][4]) {
  const int tid = threadIdx.x;
  const int w = tid >> 6, l = tid & 63;
  const int il = l & 15, kl = l >> 4;
  const int wm = w >> 1, wn = w & 1;

  auto stageA = [&](char* buf, int kt) {
#pragma unroll
    for (int c = 0; c < 4; ++c) {
      int rbase = (w << 6) + (c << 4);                     // wave-uniform
      int row = rbase + (l >> 2);
      int s = ((l & 3) - ((row >> 1) & 3)) & 3;
      gload_lds16(A + (size_t)(m0 + row) * lda + (kt << 5) + (s << 3),
                  buf + rbase * 64);
    }
  };
  auto stageB = [&](char* buf, int kt) {
#pragma unroll
    for (int c = 0; c < 2; ++c) {
      int rbase = (w << 5) + (c << 4);                     // wave-uniform
      int row = rbase + (l >> 2);
      int s = ((l & 3) - ((row >> 1) & 3)) & 3;
      gload_lds16(B + (size_t)(n0 + row) * ldb + (kt << 5) + (s << 3),
                  buf + 16384 + rbase * 64);
    }
  };
  auto loadA8 = [&](const char* buf, bf16x8 (&af)[8]) {
#pragma unroll
    for (int q = 0; q < 8; ++q) {
      int row = (wm << 7) + (q << 4) + il;
      af[q] = *(const bf16x8*)(buf + row * 64 + (((kl + (row >> 1)) & 3) << 4));
    }
  };
  auto loadB4 = [&](const char* buf, bf16x8 (&bfr)[4]) {
#pragma unroll
    for (int q = 0; q < 4; ++q) {
      int row = (wn << 6) + (q << 4) + il;
      bfr[q] = *(const bf16x8*)(buf + 16384 + row * 64 + (((kl + (row >> 1)) & 3) << 4));
    }
  };

#pragma unroll
  for (int i = 0; i < 8; ++i)
#pragma unroll
    for (int j = 0; j < 4; ++j) acc[i][j] = f32x4{0.f, 0.f, 0.f, 0.f};

  stageA(lds, 0);         stageB(lds, 0);
  stageA(lds + 24576, 1); stageB(lds + 24576, 1);
  asm volatile("s_waitcnt vmcnt(6)" ::: "memory");
  __builtin_amdgcn_s_barrier();

  int cur = 0, nx = 2;
  for (int g = 0; g < P; ++g) {
    char* cbuf = lds + cur * 24576;
    char* sbuf = lds + nx * 24576;
    bf16x8 af[8], bfr[4];
    loadA8(cbuf, af);
    loadB4(cbuf, bfr);
    if (g + 2 < P) { stageA(sbuf, g + 2); stageB(sbuf, g + 2); }
    __builtin_amdgcn_s_setprio(1);
#pragma unroll
    for (int fm = 0; fm < 8; ++fm)
#pragma unroll
      for (int fn = 0; fn < 4; ++fn)
        acc[fm][fn] = MFMA16(af[fm], bfr[fn], acc[fm][fn]);
    __builtin_amdgcn_s_setprio(0);
    if (g + 2 < P) asm volatile("s_waitcnt vmcnt(6)" ::: "memory");
    else           asm volatile("s_waitcnt vmcnt(0)" ::: "memory");
    __builtin_amdgcn_s_barrier();
    cur = (cur == 2) ? 0 : cur + 1;
    nx  = (nx  == 2) ? 0 : nx  + 1;
  }
}

// ------------------------------- gemm1 (qkv) --------------------------------
// 3072 blocks; XCD swizzle. Q/K epilogue via LDS transpose -> 16B stores.

__global__ __launch_bounds__(256, 2) void gemm_qkv_k(
    const ushort* __restrict__ xb, const ushort* __restrict__ Wp,
    ushort* __restrict__ Qb, ushort* __restrict__ Kb, ushort* __restrict__ Vt) {
  __shared__ __align__(16) char lds[73728];
  f32x4 acc[8][4];
  const int Bid = blockIdx.x;
  const int xcd = Bid & 7, idx = Bid >> 3;
  const int nt = idx % 12, pl = idx / 12;       // pl 0..31
  const int m0 = ((pl << 3) + xcd) << 8;        // 256 m-tiles * 256
  const int n0 = nt << 7;
  gemm_nt_256x128(xb, Wp, 512, 512, 16, m0, n0, lds, acc);

  const int tid = threadIdx.x, w = tid >> 6, l = tid & 63;
  const int il = l & 15, kl = l >> 4;
  const int wm = w >> 1, wn = w & 1;
  const int kq = n0 >> 9;                       // block-uniform: 0=Q 1=K 2=V
  const int br = m0 >> 8, b = br >> 6, r = br & 63;   // one (b,r) per block

  if (kq < 2) {
    // stage acc into LDS [256 i][136 pad] bf16 (69.6 KB), then wide stores.
    ushort* Pl = (ushort*)lds;
    __syncthreads();                            // mainloop LDS fully consumed
#pragma unroll
    for (int fm = 0; fm < 8; ++fm)
#pragma unroll
      for (int fn = 0; fn < 4; ++fn) {
        int ccol = (wn << 6) + (fn << 4) + il;
#pragma unroll
        for (int j = 0; j < 4; ++j) {
          int irow = (wm << 7) + (fm << 4) + (kl << 2) + j;
          Pl[irow * 136 + ccol] = f2bf(acc[fm][fn][j]);
        }
      }
    __syncthreads();
    ushort* dstb = kq ? Kb : Qb;
#pragma unroll
    for (int it = 0; it < 16; ++it) {
      int u = (it << 8) + tid;                  // 4096 units = 256 rows x 16
      int row = u >> 4, n8 = (u & 15);
      int n_full = n0 + (n8 << 3);
      int h = (n_full >> 6) & 7, d0 = n_full & 63;
      bf16x8 v = *(const bf16x8*)(Pl + row * 136 + (n8 << 3));
      size_t dst = ((size_t)((((b << 3) + h) << 8) + row) << 12) + (r << 6) + d0;
      *reinterpret_cast<bf16x8*>(&dstb[dst]) = v;   // 16B; 8 lanes = 128B run
    }
  } else {
#pragma unroll
    for (int fm = 0; fm < 8; ++fm)
#pragma unroll
      for (int fn = 0; fn < 4; ++fn) {
        int n = n0 - 1024 + (wn << 6) + (fn << 4) + il;     // h*64+d
        int h = n >> 6, d = n & 63;
        int i0 = (wm << 7) + (fm << 4) + (kl << 2);
        size_t dst = (((size_t)((((b << 3) + h) << 12)) + (r << 6) + d) << 8) + i0;
        ushort4 pk; pk.x = f2bf(acc[fm][fn][0]); pk.y = f2bf(acc[fm][fn][1]);
        pk.z = f2bf(acc[fm][fn][2]); pk.w = f2bf(acc[fm][fn][3]);
        *reinterpret_cast<ushort4*>(&Vt[dst]) = pk;   // 4 consecutive i
      }
  }
}

// ------------------------------- gemm2 (out) --------------------------------

__global__ __launch_bounds__(256, 2) void gemm_out_k(
    const ushort* __restrict__ O2, const ushort* __restrict__ W0b,
    float* __restrict__ out) {
  __shared__ __align__(16) char lds[73728];
  f32x4 acc[8][4];
  const int Bid = blockIdx.x;
  const int xcd = Bid & 7, idx = Bid >> 3;
  const int nt = idx & 3, pl = idx >> 2;        // pl 0..31
  const int m0 = ((pl << 3) + xcd) << 8;
  const int n0 = nt << 7;
  gemm_nt_256x128(O2, W0b, 512, 512, 16, m0, n0, lds, acc);

  const int tid = threadIdx.x, w = tid >> 6, l = tid & 63;
  const int il = l & 15, kl = l >> 4;
  const int wm = w >> 1, wn = w & 1;
#pragma unroll
  for (int fm = 0; fm < 8; ++fm)
#pragma unroll
    for (int fn = 0; fn < 4; ++fn) {
      int n = n0 + (wn << 6) + (fn << 4) + il;
#pragma unroll
      for (int j = 0; j < 4; ++j) {
        int m = m0 + (wm << 7) + (fm << 4) + (kl << 2) + j;
        out[(size_t)m * 512 + n] = acc[fm][fn][j];
      }
    }
}

// ---------------------- gemm_s: S partials (split-K=4) ----------------------
// 256 blocks: nt = Bid&1, z = Bid>>1 (bh*4+ks). Each block: 256x128 slab of
// S over rd-range ks*1024..+1024 (P=32). Sp[z][i][j] fp32.

__global__ __launch_bounds__(256, 2) void gemm_s_k(
    const ushort* __restrict__ Qb, const ushort* __restrict__ Kb,
    float* __restrict__ Sp) {
  __shared__ __align__(16) char lds[73728];
  f32x4 acc[8][4];
  const int Bid = blockIdx.x;
  const int nt = Bid & 1, z = Bid >> 1;         // z 0..127
  const int bh = z >> 2, ks = z & 3;
  const int n0 = nt << 7;
  const size_t base = ((size_t)bh << 20) + ((size_t)ks << 10);
  gemm_nt_256x128(Qb + base, Kb + base, 4096, 4096, 32, 0, n0, lds, acc);

  const int tid = threadIdx.x, w = tid >> 6, l = tid & 63;
  const int il = l & 15, kl = l >> 4;
  const int wm = w >> 1, wn = w & 1;
  float* o = Sp + ((size_t)z << 16);
#pragma unroll
  for (int fm = 0; fm < 8; ++fm)
#pragma unroll
    for (int fn = 0; fn < 4; ++fn) {
      int n = n0 + (wn << 6) + (fn << 4) + il;
#pragma unroll
      for (int j = 0; j < 4; ++j) {
        int m = (wm << 7) + (fm << 4) + (kl << 2) + j;
        o[(size_t)m * 256 + n] = acc[fm][fn][j];
      }
    }
}

// ------------------------- softmax (wave per row) ---------------------------
// P[bh][i][j] = softmax_j(sum_{ks=0..3} Sp[4bh+ks] / 64), bf16 with 1/sum.

__global__ void softmax_k(const float* __restrict__ Sp, ushort* __restrict__ Pb) {
  const int w = threadIdx.x >> 6, l = threadIdx.x & 63;
  const int row = (blockIdx.x << 2) + w;        // 0..8191
  const int bh = row >> 8, i = row & 255;
  const float4* p0 = reinterpret_cast<const float4*>(
      Sp + (((size_t)bh << 2) << 16) + ((size_t)i << 8)) + l;
  float4 a = p0[0], b2 = p0[16384], c = p0[32768], d = p0[49152];
  const float scale = 0.015625f;
  float s0 = (a.x + b2.x + c.x + d.x) * scale;
  float s1 = (a.y + b2.y + c.y + d.y) * scale;
  float s2 = (a.z + b2.z + c.z + d.z) * scale;
  float s3 = (a.w + b2.w + c.w + d.w) * scale;
  float m = fmaxf(fmaxf(s0, s1), fmaxf(s2, s3));
#pragma unroll
  for (int d2 = 1; d2 < 64; d2 <<= 1) m = fmaxf(m, __shfl_xor(m, d2));
  float e0 = __expf(s0 - m), e1 = __expf(s1 - m);
  float e2 = __expf(s2 - m), e3 = __expf(s3 - m);
  float sum = e0 + e1 + e2 + e3;
#pragma unroll
  for (int d2 = 1; d2 < 64; d2 <<= 1) sum += __shfl_xor(sum, d2);
  float r = 1.0f / sum;
  ushort4 p; p.x = f2bf(e0 * r); p.y = f2bf(e1 * r);
  p.z = f2bf(e2 * r); p.w = f2bf(e3 * r);
  reinterpret_cast<ushort4*>(Pb + ((size_t)bh << 16) + ((size_t)i << 8))[l] = p;
}

// ---------------------- gemm_pv: O = P V  (A=Vt, B=P) -----------------------

__global__ __launch_bounds__(256, 2) void gemm_pv_k(
    const ushort* __restrict__ Vt, const ushort* __restrict__ Pb,
    ushort* __restrict__ O2) {
  __shared__ __align__(16) char lds[73728];
  f32x4 acc[8][4];
  const int Bid = blockIdx.x;
  const int xcd = Bid & 7, idx = Bid >> 3;      // idx 0..127
  const int sub = idx & 31, grp = idx >> 5;     // sub: mt*2+nt, grp 0..3
  const int bh = (grp << 3) + xcd, b = bh >> 3, h = bh & 7;
  const int m0 = (sub >> 1) << 8;               // rd tile (16 x 256)
  const int n0 = (sub & 1) << 7;                // i tile (2 x 128)
  gemm_nt_256x128(Vt + ((size_t)bh << 20), Pb + ((size_t)bh << 16),
                  256, 256, 8, m0, n0, lds, acc);

  const int tid = threadIdx.x, w = tid >> 6, l = tid & 63;
  const int il = l & 15, kl = l >> 4;
  const int wm = w >> 1, wn = w & 1;
#pragma unroll
  for (int fm = 0; fm < 8; ++fm) {
    int rd0 = m0 + (wm << 7) + (fm << 4) + (kl << 2);
    int r = rd0 >> 6, d0 = rd0 & 63;
#pragma unroll
    for (int fn = 0; fn < 4; ++fn) {
      int i = n0 + (wn << 6) + (fn << 4) + il;
      ushort4 pk; pk.x = f2bf(acc[fm][fn][0]); pk.y = f2bf(acc[fm][fn][1]);
      pk.z = f2bf(acc[fm][fn][2]); pk.w = f2bf(acc[fm][fn][3]);
      *reinterpret_cast<ushort4*>(
          O2 + ((size_t)((((b << 6) + r) << 8) + i) << 9) + (h << 6) + d0) = pk;
    }
  }
}

// ------------------------------- launcher -----------------------------------

extern "C" void kernel_launch(void* const* d_in, const int* in_sizes, int n_in,
                              void* d_out, int out_size, void* d_ws, size_t ws_size,
                              hipStream_t stream) {
  const float* x    = (const float*)d_in[0];
  const float* Wqkv = (const float*)d_in[1];
  const float* W0   = (const float*)d_in[2];
  float* out = (float*)d_out;

  char* ws = (char*)d_ws;
  ushort* xb  = (ushort*)(ws);                    // 67,108,864 B (-> Sp -> O2)
  ushort* Wp  = (ushort*)(ws + 67108864);         //  1,572,864
  ushort* W0b = (ushort*)(ws + 68681728);         //    524,288
  ushort* Qb  = (ushort*)(ws + 69206016);         // 67,108,864 (-> Pb)
  ushort* Kb  = (ushort*)(ws + 136314880);        // 67,108,864
  ushort* Vt  = (ushort*)(ws + 203423744);        // 67,108,864  -> total 270,532,608
  if (ws_size < 270532608ull) return;             // workspace too small: fail visibly

  cast_f32_to_bf16<<<2048, 256, 0, stream>>>(x, xb, 8388608);
  prep_k<<<832, 256, 0, stream>>>(Wqkv, Wp, W0, W0b);

  gemm_qkv_k<<<3072, 256, 0, stream>>>(xb, Wp, Qb, Kb, Vt);

  float*  Sp = (float*)xb;                        // xb dead after gemm1 (33.6 MB)
  ushort* Pb = Qb;                                // Qb dead after gemm_s (4.2 MB)
  ushort* O2 = xb;                                // Sp dead after softmax (64 MB)

  gemm_s_k<<<256, 256, 0, stream>>>(Qb, Kb, Sp);
  softmax_k<<<2048, 256, 0, stream>>>(Sp, Pb);
  gemm_pv_k<<<1024, 256, 0, stream>>>(Vt, Pb, O2);

  gemm_out_k<<<1024, 256, 0, stream>>>(O2, W0b, out);
}